// Round 5
// baseline (168.386 us; speedup 1.0000x reference)
//
#include <hip/hip_runtime.h>
#include <math.h>

#define HW_N   3136
#define W_DIM  56
#define C_IN   256
#define C_R    32
#define C_OUT  256
#define C_ALL  320
#define K2D    49
#define RS     40        // attn t-row stride in halfs (80 B, 16B-aligned)
#define BN_EPS 1e-5f

typedef _Float16 h2 __attribute__((ext_vector_type(2)));
typedef _Float16 h4 __attribute__((ext_vector_type(4)));
typedef _Float16 h8 __attribute__((ext_vector_type(8)));
typedef __fp16  g2 __attribute__((ext_vector_type(2)));   // cvt_pkrtz return type
typedef __fp16  g4 __attribute__((ext_vector_type(4)));
typedef __fp16  g8 __attribute__((ext_vector_type(8)));
typedef float   f4 __attribute__((ext_vector_type(4)));
typedef unsigned int u32;
typedef unsigned int u32x4 __attribute__((ext_vector_type(4)));

__device__ __forceinline__ h2 pkrtz(float a, float b) {
    g2 r = __builtin_amdgcn_cvt_pkrtz(a, b);
    return __builtin_bit_cast(h2, r);
}

__device__ __forceinline__ g8 pack8(float4 a, float4 b) {
    g2 p0 = __builtin_amdgcn_cvt_pkrtz(a.x, a.y);
    g2 p1 = __builtin_amdgcn_cvt_pkrtz(a.z, a.w);
    g2 p2 = __builtin_amdgcn_cvt_pkrtz(b.x, b.y);
    g2 p3 = __builtin_amdgcn_cvt_pkrtz(b.z, b.w);
    g8 o;
    o[0] = p0[0]; o[1] = p0[1]; o[2] = p1[0]; o[3] = p1[1];
    o[4] = p2[0]; o[5] = p2[1]; o[6] = p3[0]; o[7] = p3[1];
    return o;
}

__device__ __forceinline__ int refl(int v) {
    v = (v < 0) ? -v : v;
    return (v > 55) ? (110 - v) : v;
}

// Wave-local "barrier": tbuf[w]/pk[w] are wave-private; DS pipe is in-order
// per wave, so we only need the compiler fence + lgkmcnt drain.
// NOTE: does NOT drain vmcnt -> prefetched global loads stay in flight.
__device__ __forceinline__ void wave_fence() {
    asm volatile("s_waitcnt lgkmcnt(0)" ::: "memory");
}

// ---------------------------------------------------------------------------
// Kernel 1: fused transpose + MFMA conv1x1 -> xall16[b][pos][320] f16.
// v5: SAME 32-pos x 320-co block tile (round-3 lesson: never shrink it),
// but 512 threads / 8 waves: wave w does mt = w&1 (16-row half) x
// co-group w>>1 (80 cols). Per-wave MFMA 80->40, waves/SIMD 1.5->3.1,
// staging per block unchanged (same coalescing, half the loads per thread).
// Weight loads duplicate across mt-pairs (L2-hot, acceptable).
// ---------------------------------------------------------------------------
__global__ __launch_bounds__(512) void k_conv_mfma(
    const float* __restrict__ x,
    const float* __restrict__ w1c, const float* __restrict__ w2c,
    const float* __restrict__ w3c,
    const float* __restrict__ b1c, const float* __restrict__ b2c,
    const float* __restrict__ b3c, __fp16* __restrict__ xall16)
{
    __shared__ __align__(16) _Float16 smem[32 * 328];   // staging 16KB / cs 21KB
    const int t = threadIdx.x, w = t >> 6, lane = t & 63;
    const int quad = lane >> 4, l16 = lane & 15;
    const int b = blockIdx.z, pos0 = blockIdx.x * 32;
    const int mt = w & 1;            // 16-row half of the 32-pos tile
    const int cg = w >> 1;           // co-group (80 cols)

    // ---- stage x[b][:][pos0..pos0+31] -> smem h8 slots [p][g], XOR-swizzled
    // 512 threads: p = t&31 (same 32-lane pos coalescing), gb = t>>5 (0..15)
    {
        const int p  = t & 31;
        const int gb = t >> 5;               // 0..15
        const float* xp = x + (size_t)b * C_IN * HW_N + pos0 + p;
#pragma unroll
        for (int i = 0; i < 2; ++i) {
            const int g = i * 16 + gb;
            const int ci = g * 8;
            float v[8];
#pragma unroll
            for (int j = 0; j < 8; ++j) v[j] = xp[(size_t)(ci + j) * HW_N];
            g8 o;
#pragma unroll
            for (int jj = 0; jj < 4; ++jj) {
                const g2 pr = __builtin_amdgcn_cvt_pkrtz(v[2 * jj], v[2 * jj + 1]);
                o[2 * jj] = pr[0]; o[2 * jj + 1] = pr[1];
            }
            *(g8*)((__fp16*)smem + (size_t)(p * 32 + (g ^ (p & 7))) * 8) = o;
        }
    }
    __syncthreads();

    // weights rows + bias for this wave's 5 co-tiles (co = cg*80 + nt*16 + l16)
    const float* wrow[5]; float bias[5];
#pragma unroll
    for (int nt = 0; nt < 5; ++nt) {
        const int co = cg * 80 + nt * 16 + l16;
        wrow[nt] = (co < 32) ? (w1c + co * C_IN)
                 : (co < 64) ? (w2c + (co - 32) * C_IN)
                             : (w3c + (co - 64) * C_IN);
        bias[nt] = (co < 32) ? b1c[co] : (co < 64) ? b2c[co - 32] : b3c[co - 64];
    }

    f4 acc[5];
#pragma unroll
    for (int nt = 0; nt < 5; ++nt) acc[nt] = (f4){0.f, 0.f, 0.f, 0.f};

    const int xo = l16 & 7;
#pragma unroll
    for (int ks = 0; ks < 8; ++ks) {
        g8 bf[5];
#pragma unroll
        for (int nt = 0; nt < 5; ++nt) {
            const float* wp = wrow[nt] + ks * 32 + quad * 8;
            bf[nt] = pack8(*(const float4*)wp, *(const float4*)(wp + 4));
        }
        const int row = mt * 16 + l16;
        const g8 af = *(const g8*)((const __fp16*)smem
                      + (size_t)(row * 32 + ((ks * 4 + quad) ^ xo)) * 8);
#pragma unroll
        for (int nt = 0; nt < 5; ++nt)
            acc[nt] = __builtin_amdgcn_mfma_f32_16x16x32_f16(af, bf[nt], acc[nt], 0, 0, 0);
    }
    __syncthreads();   // all A-frag reads done before smem is reused

    // ---- epilogue: C-frags -> smem f16 [32][328], then coalesced h8 stores
#pragma unroll
    for (int nt = 0; nt < 5; ++nt) {
        const int co = cg * 80 + nt * 16 + l16;
#pragma unroll
        for (int r = 0; r < 4; ++r) {
            const int row = mt * 16 + quad * 4 + r;
            smem[row * 328 + co] = (_Float16)(acc[nt][r] + bias[nt]);
        }
    }
    __syncthreads();
#pragma unroll
    for (int i = 0; i < 3; ++i) {
        const int idx = i * 512 + t;        // 0..1279 = 32 rows x 40 h8
        if (idx < 1280) {
            const int row = idx / 40, c8 = idx - row * 40;
            const g8 v = *(const g8*)((const __fp16*)smem + row * 328 + c8 * 8);
            *(g8*)(xall16 + ((size_t)b * HW_N + pos0 + row) * C_ALL + c8 * 8) = v;
        }
    }
}

// ---------------------------------------------------------------------------
// Kernel 2: fused attention + output transpose. One wave per pixel,
// 4 waves/block; single block barrier at the very end for the transpose.
// v4 (measured 42.1us, down from 52.6 baseline):
//  - weight frags (cw1/cw2) + BN2 constants hoisted to kernel entry
//  - phase 1: one v_fma_mix per channel + packed-f16 ReLU after pkrtz (exact)
//  - phase 5: first 12 V-rows prefetched right after phase-1 fence; the
//    lgkmcnt-only fences keep them in flight across GEMM1/BN2/GEMM2/softmax
// UNCHANGED this round (single-variable experiment on k_conv).
// ---------------------------------------------------------------------------
__global__ __launch_bounds__(256) void k_attn(
    const __fp16* __restrict__ xq,
    const float* __restrict__ bn1_g, const float* __restrict__ bn1_b,
    const float* __restrict__ bn1_m, const float* __restrict__ bn1_v,
    const float* __restrict__ cw1,
    const float* __restrict__ bn2_g, const float* __restrict__ bn2_b,
    const float* __restrict__ bn2_m, const float* __restrict__ bn2_v,
    const float* __restrict__ cw2, const float* __restrict__ cw2_b,
    float* __restrict__ out)
{
    __shared__ __align__(16) _Float16 tbuf[4][64 * RS];   // 64 rows (49 valid)
    __shared__ int pk[4][52];
    const int tid = threadIdx.x;
    const int w = tid >> 6, lane = tid & 63;
    const int b = blockIdx.y;
    const int bid  = blockIdx.x;                 // 0..783
    const int posb = (bid & 7) * 98 + (bid >> 3);   // XCD-contiguous spans
    const int pos0 = posb * 4;
    const int pos  = pos0 + w;
    const int y0 = pos / W_DIM, x0 = pos - y0 * W_DIM;
    const __fp16* __restrict__ base16 = xq + (size_t)b * HW_N * C_ALL;
    _Float16* tb = tbuf[w];
    // per-wave output staging aliases tbuf rows 49..63 (written only after
    // the wave's last read of rows <49; wave-private until __syncthreads)
    float* stage_w = (float*)(tb + 49 * RS);
    (void)cw2_b;   // cancels along the softmax axis

    const int quad = lane >> 4, l16 = lane & 15;

    // ---- hoisted: GEMM weight fragments + BN2 constants (phase-independent)
    g8 bf1[2], bf2[2];
    float iv2c[2], bt2c[2];
#pragma unroll
    for (int nt = 0; nt < 2; ++nt) {
        const float* wr1 = cw1 + (nt * 16 + l16) * C_R + quad * 8;
        bf1[nt] = pack8(*(const float4*)wr1, *(const float4*)(wr1 + 4));
        const float* wr2 = cw2 + (nt * 16 + l16) * C_R + quad * 8;
        bf2[nt] = pack8(*(const float4*)wr2, *(const float4*)(wr2 + 4));
        const int o = nt * 16 + l16;
        iv2c[nt] = bn2_g[o] * rsqrtf(bn2_v[o] + BN_EPS);
        bt2c[nt] = bn2_b[o] - bn2_m[o] * iv2c[nt];
    }

    // ---- phase 1: t[k][c] = relu(bn1(x1[c] - x2[pk(k)][c])) in f32, f16 pack
    // lane = r16*4 + c8: 8 channels per lane (16B loads), 16 rows per pass.
    {
        const int c8  = lane & 3;        // 8-ch block (ch = c8*8 .. +7)
        const int r16 = lane >> 2;       // row-in-pass 0..15
        const int cb  = c8 * 8;
        float niv[8], a1[8];             // niv = -iv; a1 = x1*iv + bt (f32)
        {
            float gg[8], bb_[8], mm[8], vv[8];
            *(float4*)(gg)      = *(const float4*)(bn1_g + cb);
            *(float4*)(gg + 4)  = *(const float4*)(bn1_g + cb + 4);
            *(float4*)(bb_)     = *(const float4*)(bn1_b + cb);
            *(float4*)(bb_ + 4) = *(const float4*)(bn1_b + cb + 4);
            *(float4*)(mm)      = *(const float4*)(bn1_m + cb);
            *(float4*)(mm + 4)  = *(const float4*)(bn1_m + cb + 4);
            *(float4*)(vv)      = *(const float4*)(bn1_v + cb);
            *(float4*)(vv + 4)  = *(const float4*)(bn1_v + cb + 4);
            const h8 x1v = *(const h8*)(base16 + (size_t)pos * C_ALL + cb);
#pragma unroll
            for (int j = 0; j < 8; ++j) {
                const float iv = gg[j] * rsqrtf(vv[j] + BN_EPS);
                const float bt = bb_[j] - mm[j] * iv;
                a1[j]  = fmaf((float)x1v[j], iv, bt);
                niv[j] = -iv;
            }
        }
        const h2 hz = {};

        auto bnrow = [&](int k) {
            const int dy = k / 7, dx = k - dy * 7;
            const int rp = refl(y0 + dy - 3) * W_DIM + refl(x0 + dx - 3);
            if (c8 == 0) pk[w][k] = rp;
            const h8 x2v = *(const h8*)(base16 + (size_t)rp * C_ALL + 32 + cb);
            float tv[8];
#pragma unroll
            for (int j = 0; j < 8; ++j)
                tv[j] = fmaf((float)x2v[j], niv[j], a1[j]);   // v_fma_mix
            h2 p0 = pkrtz(tv[0], tv[1]), p1 = pkrtz(tv[2], tv[3]);
            h2 p2 = pkrtz(tv[4], tv[5]), p3 = pkrtz(tv[6], tv[7]);
            p0 = __builtin_elementwise_max(p0, hz);
            p1 = __builtin_elementwise_max(p1, hz);
            p2 = __builtin_elementwise_max(p2, hz);
            p3 = __builtin_elementwise_max(p3, hz);
            u32x4 o;
            o[0] = __builtin_bit_cast(u32, p0);
            o[1] = __builtin_bit_cast(u32, p1);
            o[2] = __builtin_bit_cast(u32, p2);
            o[3] = __builtin_bit_cast(u32, p3);
            *(u32x4*)&tb[k * RS + cb] = o;          // 16B-aligned (80B rows)
        };
#pragma unroll
        for (int j = 0; j < 3; ++j) bnrow(j * 16 + r16);   // k = 0..47, no guard
        if (r16 == 0) bnrow(48);                           // tail row
    }
    wave_fence();

    // ---- early V-issue for phase 5 (addresses known now; loads stay in
    // flight across the lgkmcnt-only fences below)
    const int hn5 = lane & 31;       // head == 8-ch block index
    const int hf5 = lane >> 5;       // 0: even k, 1: odd k
    const __fp16* vb5 = base16 + 64 + hn5 * 8;
    h8 pre[12];
#pragma unroll
    for (int i = 0; i < 12; ++i)
        pre[i] = *(const h8*)(vb5 + (size_t)pk[w][2 * i + hf5] * C_ALL);

    f4 acc[4][2];

    // ---- phase 2 (GEMM1): Y1[k][o] = sum_c t[k][c] * cw1[o][c]
#pragma unroll
    for (int mt = 0; mt < 4; ++mt) {
        acc[mt][0] = (f4){0.f, 0.f, 0.f, 0.f};
        acc[mt][1] = (f4){0.f, 0.f, 0.f, 0.f};
        const g8 af = *(const g8*)((const __fp16*)tb + (mt * 16 + l16) * RS + quad * 8);
        acc[mt][0] = __builtin_amdgcn_mfma_f32_16x16x32_f16(af, bf1[0], acc[mt][0], 0, 0, 0);
        acc[mt][1] = __builtin_amdgcn_mfma_f32_16x16x32_f16(af, bf1[1], acc[mt][1], 0, 0, 0);
    }
    wave_fence();

    // ---- BN2 + ReLU on C-frags (col = output channel o), write y2[k][o]
#pragma unroll
    for (int nt = 0; nt < 2; ++nt) {
        const int o = nt * 16 + l16;
        const float iv = iv2c[nt], bt = bt2c[nt];
#pragma unroll
        for (int mt = 0; mt < 4; ++mt)
#pragma unroll
            for (int r = 0; r < 4; ++r) {
                const int row = mt * 16 + quad * 4 + r;
                tb[row * RS + o] = (_Float16)fmaxf(acc[mt][nt][r] * iv + bt, 0.f);
            }
    }
    wave_fence();

    // ---- phase 3 (GEMM2): logits[k][h] = sum_o y2[k][o] * cw2[h][o]
#pragma unroll
    for (int mt = 0; mt < 4; ++mt) {
        acc[mt][0] = (f4){0.f, 0.f, 0.f, 0.f};
        acc[mt][1] = (f4){0.f, 0.f, 0.f, 0.f};
        const g8 af = *(const g8*)((const __fp16*)tb + (mt * 16 + l16) * RS + quad * 8);
        acc[mt][0] = __builtin_amdgcn_mfma_f32_16x16x32_f16(af, bf2[0], acc[mt][0], 0, 0, 0);
        acc[mt][1] = __builtin_amdgcn_mfma_f32_16x16x32_f16(af, bf2[1], acc[mt][1], 0, 0, 0);
    }
    wave_fence();

    // ---- phase 4: softmax over k per head h = nt*16+l16; k = mt*16+quad*4+r
    // bias cancels along k; logits are O(1) for this problem -> no max-shift.
    // wgt writes limited to rows < 49 (stage alias lives in rows 49..63).
#pragma unroll
    for (int nt = 0; nt < 2; ++nt) {
        float s = 0.f;
#pragma unroll
        for (int mt = 0; mt < 4; ++mt)
#pragma unroll
            for (int r = 0; r < 4; ++r) {
                const int k = mt * 16 + quad * 4 + r;
                const float e = (k < K2D) ? __expf(acc[mt][nt][r]) : 0.f;
                acc[mt][nt][r] = e;
                s += e;
            }
        s += __shfl_xor(s, 16, 64);
        s += __shfl_xor(s, 32, 64);
        const float rs = 1.f / s;
        const int o = nt * 16 + l16;
#pragma unroll
        for (int mt = 0; mt < 4; ++mt)
#pragma unroll
            for (int r = 0; r < 4; ++r) {
                const int row = mt * 16 + quad * 4 + r;
                if (row < K2D)
                    tb[row * RS + o] = (_Float16)(acc[mt][nt][r] * rs);
            }
    }
    wave_fence();

    // ---- phase 5: out[c] = sum_k x3[pk[k]][c] * wgt[k][c>>3]
    // half-wave split: lanes 0..31 even k, 32..63 odd k; 8 ch/lane (16B loads)
    {
        float a0 = 0.f, a1 = 0.f, a2 = 0.f, a3 = 0.f;
        float a4 = 0.f, a5 = 0.f, a6 = 0.f, a7 = 0.f;
#pragma unroll
        for (int i = 0; i < 12; ++i) {                     // prefetched rows
            const int k = 2 * i + hf5;
            const float wv = (float)tb[k * RS + hn5];
            const h8 v = pre[i];
            a0 = fmaf((float)v[0], wv, a0);
            a1 = fmaf((float)v[1], wv, a1);
            a2 = fmaf((float)v[2], wv, a2);
            a3 = fmaf((float)v[3], wv, a3);
            a4 = fmaf((float)v[4], wv, a4);
            a5 = fmaf((float)v[5], wv, a5);
            a6 = fmaf((float)v[6], wv, a6);
            a7 = fmaf((float)v[7], wv, a7);
        }
#pragma unroll 6
        for (int i = 12; i < 24; ++i) {
            const int k = 2 * i + hf5;                     // <= 47, always valid
            const int rp = pk[w][k];
            const float wv = (float)tb[k * RS + hn5];
            const h8 v = *(const h8*)(vb5 + (size_t)rp * C_ALL);
            a0 = fmaf((float)v[0], wv, a0);
            a1 = fmaf((float)v[1], wv, a1);
            a2 = fmaf((float)v[2], wv, a2);
            a3 = fmaf((float)v[3], wv, a3);
            a4 = fmaf((float)v[4], wv, a4);
            a5 = fmaf((float)v[5], wv, a5);
            a6 = fmaf((float)v[6], wv, a6);
            a7 = fmaf((float)v[7], wv, a7);
        }
        if (hf5 == 0) {                                    // tail k = 48
            const int rp = pk[w][48];
            const float wv = (float)tb[48 * RS + hn5];
            const h8 v = *(const h8*)(vb5 + (size_t)rp * C_ALL);
            a0 = fmaf((float)v[0], wv, a0);
            a1 = fmaf((float)v[1], wv, a1);
            a2 = fmaf((float)v[2], wv, a2);
            a3 = fmaf((float)v[3], wv, a3);
            a4 = fmaf((float)v[4], wv, a4);
            a5 = fmaf((float)v[5], wv, a5);
            a6 = fmaf((float)v[6], wv, a6);
            a7 = fmaf((float)v[7], wv, a7);
        }
        a0 += __shfl_xor(a0, 32, 64);
        a1 += __shfl_xor(a1, 32, 64);
        a2 += __shfl_xor(a2, 32, 64);
        a3 += __shfl_xor(a3, 32, 64);
        a4 += __shfl_xor(a4, 32, 64);
        a5 += __shfl_xor(a5, 32, 64);
        a6 += __shfl_xor(a6, 32, 64);
        a7 += __shfl_xor(a7, 32, 64);
        if (hf5 == 0) {
            f4 o0 = {a0, a1, a2, a3};
            f4 o1 = {a4, a5, a6, a7};
            *(f4*)&stage_w[hn5 * 8]     = o0;
            *(f4*)&stage_w[hn5 * 8 + 4] = o1;
        }
    }
    __syncthreads();

    // ---- transpose through LDS: store out[b][c][pos0..pos0+3]
    {
        const int c = tid;
        const float* st0 = (const float*)(tbuf[0] + 49 * RS);
        const float* st1 = (const float*)(tbuf[1] + 49 * RS);
        const float* st2 = (const float*)(tbuf[2] + 49 * RS);
        const float* st3 = (const float*)(tbuf[3] + 49 * RS);
        float4 o;
        o.x = st0[c]; o.y = st1[c];
        o.z = st2[c]; o.w = st3[c];
        *(float4*)(out + ((size_t)b * C_OUT + c) * HW_N + pos0) = o;
    }
}

// ---------------------------------------------------------------------------
extern "C" void kernel_launch(void* const* d_in, const int* in_sizes, int n_in,
                              void* d_out, int out_size, void* d_ws, size_t ws_size,
                              hipStream_t stream)
{
    const float* x     = (const float*)d_in[0];
    const float* w1c   = (const float*)d_in[1];
    const float* b1c   = (const float*)d_in[2];
    const float* w2c   = (const float*)d_in[3];
    const float* b2c   = (const float*)d_in[4];
    const float* w3c   = (const float*)d_in[5];
    const float* b3c   = (const float*)d_in[6];
    const float* bn1_g = (const float*)d_in[7];
    const float* bn1_b = (const float*)d_in[8];
    const float* bn1_m = (const float*)d_in[9];
    const float* bn1_v = (const float*)d_in[10];
    const float* cw1   = (const float*)d_in[11];
    const float* bn2_g = (const float*)d_in[12];
    const float* bn2_b = (const float*)d_in[13];
    const float* bn2_m = (const float*)d_in[14];
    const float* bn2_v = (const float*)d_in[15];
    const float* cw2   = (const float*)d_in[16];
    const float* cw2_b = (const float*)d_in[17];

    __fp16* xall16 = (__fp16*)d_ws;                         // [4][3136][320] f16

    k_conv_mfma<<<dim3(98, 1, 4), 512, 0, stream>>>(x, w1c, w2c, w3c,
                                                    b1c, b2c, b3c, xall16);
    k_attn<<<dim3(784, 4, 1), 256, 0, stream>>>(xall16,
        bn1_g, bn1_b, bn1_m, bn1_v, cw1,
        bn2_g, bn2_b, bn2_m, bn2_v, cw2, cw2_b, (float*)d_out);
}

// Round 6
// 164.414 us; speedup vs baseline: 1.0242x; 1.0242x over previous
//
#include <hip/hip_runtime.h>
#include <math.h>

#define HW_N   3136
#define W_DIM  56
#define C_IN   256
#define C_R    32
#define C_OUT  256
#define C_ALL  320
#define K2D    49
#define RS     40        // attn t-row stride in halfs (80 B, 16B-aligned)
#define BN_EPS 1e-5f

typedef _Float16 h2 __attribute__((ext_vector_type(2)));
typedef _Float16 h4 __attribute__((ext_vector_type(4)));
typedef _Float16 h8 __attribute__((ext_vector_type(8)));
typedef __fp16  g2 __attribute__((ext_vector_type(2)));   // cvt_pkrtz return type
typedef __fp16  g4 __attribute__((ext_vector_type(4)));
typedef __fp16  g8 __attribute__((ext_vector_type(8)));
typedef float   f4 __attribute__((ext_vector_type(4)));
typedef unsigned int u32;
typedef unsigned int u32x4 __attribute__((ext_vector_type(4)));

__device__ __forceinline__ h2 pkrtz(float a, float b) {
    g2 r = __builtin_amdgcn_cvt_pkrtz(a, b);
    return __builtin_bit_cast(h2, r);
}

__device__ __forceinline__ g8 pack8(float4 a, float4 b) {
    g2 p0 = __builtin_amdgcn_cvt_pkrtz(a.x, a.y);
    g2 p1 = __builtin_amdgcn_cvt_pkrtz(a.z, a.w);
    g2 p2 = __builtin_amdgcn_cvt_pkrtz(b.x, b.y);
    g2 p3 = __builtin_amdgcn_cvt_pkrtz(b.z, b.w);
    g8 o;
    o[0] = p0[0]; o[1] = p0[1]; o[2] = p1[0]; o[3] = p1[1];
    o[4] = p2[0]; o[5] = p2[1]; o[6] = p3[0]; o[7] = p3[1];
    return o;
}

__device__ __forceinline__ int refl(int v) {
    v = (v < 0) ? -v : v;
    return (v > 55) ? (110 - v) : v;
}

// Wave-local "barrier": tbuf[w]/pk[w] are wave-private; DS pipe is in-order
// per wave, so we only need the compiler fence + lgkmcnt drain.
// NOTE: does NOT drain vmcnt -> prefetched global loads stay in flight.
__device__ __forceinline__ void wave_fence() {
    asm volatile("s_waitcnt lgkmcnt(0)" ::: "memory");
}

// ---------------------------------------------------------------------------
// Kernel 1: fused transpose + MFMA conv1x1 -> xall16[b][pos][320] f16.
// 32-pos x 320-co tile per block, grid (98,1,4), 256 threads. PROVEN ~18-25us.
// ROUND-3 LESSON: 16-pos retile (784 blocks) regressed to 43us.
// ROUND-5 LESSON: 512-thread 8-wave split regressed to ~37us — per-wave
// critical path is the stage+weight-gather latency chain, which the split
// left intact while doubling weight-load issue. DO NOT re-tile this kernel
// without a new mechanism (weight pre-conversion / stage-compute overlap).
// ---------------------------------------------------------------------------
__global__ __launch_bounds__(256) void k_conv_mfma(
    const float* __restrict__ x,
    const float* __restrict__ w1c, const float* __restrict__ w2c,
    const float* __restrict__ w3c,
    const float* __restrict__ b1c, const float* __restrict__ b2c,
    const float* __restrict__ b3c, __fp16* __restrict__ xall16)
{
    __shared__ __align__(16) _Float16 smem[32 * 328];   // staging 16KB / cs 21KB
    const int t = threadIdx.x, w = t >> 6, lane = t & 63;
    const int quad = lane >> 4, l16 = lane & 15;
    const int b = blockIdx.z, pos0 = blockIdx.x * 32;

    // ---- stage x[b][:][pos0..pos0+31] -> smem h8 slots [p][g], XOR-swizzled
    {
        const int p = t & 31;
        const int gb = t >> 5;               // 0..7
        const float* xp = x + (size_t)b * C_IN * HW_N + pos0 + p;
#pragma unroll
        for (int i = 0; i < 4; ++i) {
            const int g = i * 8 + gb;
            const int ci = g * 8;
            float v[8];
#pragma unroll
            for (int j = 0; j < 8; ++j) v[j] = xp[(size_t)(ci + j) * HW_N];
            g8 o;
#pragma unroll
            for (int jj = 0; jj < 4; ++jj) {
                const g2 pr = __builtin_amdgcn_cvt_pkrtz(v[2 * jj], v[2 * jj + 1]);
                o[2 * jj] = pr[0]; o[2 * jj + 1] = pr[1];
            }
            *(g8*)((__fp16*)smem + (size_t)(p * 32 + (g ^ (p & 7))) * 8) = o;
        }
    }
    __syncthreads();

    // weights rows + bias for this wave's 5 co-tiles (co = w*80 + nt*16 + l16)
    const float* wrow[5]; float bias[5];
#pragma unroll
    for (int nt = 0; nt < 5; ++nt) {
        const int co = w * 80 + nt * 16 + l16;
        wrow[nt] = (co < 32) ? (w1c + co * C_IN)
                 : (co < 64) ? (w2c + (co - 32) * C_IN)
                             : (w3c + (co - 64) * C_IN);
        bias[nt] = (co < 32) ? b1c[co] : (co < 64) ? b2c[co - 32] : b3c[co - 64];
    }

    f4 acc[2][5];
#pragma unroll
    for (int mt = 0; mt < 2; ++mt)
#pragma unroll
        for (int nt = 0; nt < 5; ++nt) acc[mt][nt] = (f4){0.f, 0.f, 0.f, 0.f};

    const int xo = l16 & 7;
#pragma unroll
    for (int ks = 0; ks < 8; ++ks) {
        g8 bf[5];
#pragma unroll
        for (int nt = 0; nt < 5; ++nt) {
            const float* wp = wrow[nt] + ks * 32 + quad * 8;
            bf[nt] = pack8(*(const float4*)wp, *(const float4*)(wp + 4));
        }
#pragma unroll
        for (int mt = 0; mt < 2; ++mt) {
            const int row = mt * 16 + l16;
            const g8 af = *(const g8*)((const __fp16*)smem
                          + (size_t)(row * 32 + ((ks * 4 + quad) ^ xo)) * 8);
#pragma unroll
            for (int nt = 0; nt < 5; ++nt)
                acc[mt][nt] = __builtin_amdgcn_mfma_f32_16x16x32_f16(af, bf[nt], acc[mt][nt], 0, 0, 0);
        }
    }
    __syncthreads();   // all A-frag reads done before smem is reused

    // ---- epilogue: C-frags -> smem f16 [32][328], then coalesced h8 stores
#pragma unroll
    for (int mt = 0; mt < 2; ++mt)
#pragma unroll
        for (int nt = 0; nt < 5; ++nt) {
            const int co = w * 80 + nt * 16 + l16;
#pragma unroll
            for (int r = 0; r < 4; ++r) {
                const int row = mt * 16 + quad * 4 + r;
                smem[row * 328 + co] = (_Float16)(acc[mt][nt][r] + bias[nt]);
            }
        }
    __syncthreads();
#pragma unroll
    for (int i = 0; i < 5; ++i) {
        const int idx = i * 256 + t;        // 0..1279 = 32 rows x 40 h8
        const int row = idx / 40, c8 = idx - row * 40;
        const g8 v = *(const g8*)((const __fp16*)smem + row * 328 + c8 * 8);
        *(g8*)(xall16 + ((size_t)b * HW_N + pos0 + row) * C_ALL + c8 * 8) = v;
    }
}

// ---------------------------------------------------------------------------
// Kernel 2: fused attention + output transpose. One wave per pixel,
// 4 waves/block; single block barrier at the very end for the transpose.
// v6 changes vs v4 (measured 42.1us):
//  - phase 5 V-prefetch extended from 12 rows to ALL 24 + tail row 48
//    (pre[24] + preT, +~100 VGPR; VGPR headroom proven: v4 used only 64,
//    occupancy 2.6 waves/SIMD < the 3-wave cap at ~170 VGPR). All V
//    gathers issue right after phase 1 and land under GEMM1/BN2/GEMM2/
//    softmax; phase 5 becomes pure VALU+LDS.
// ---------------------------------------------------------------------------
__global__ __launch_bounds__(256) void k_attn(
    const __fp16* __restrict__ xq,
    const float* __restrict__ bn1_g, const float* __restrict__ bn1_b,
    const float* __restrict__ bn1_m, const float* __restrict__ bn1_v,
    const float* __restrict__ cw1,
    const float* __restrict__ bn2_g, const float* __restrict__ bn2_b,
    const float* __restrict__ bn2_m, const float* __restrict__ bn2_v,
    const float* __restrict__ cw2, const float* __restrict__ cw2_b,
    float* __restrict__ out)
{
    __shared__ __align__(16) _Float16 tbuf[4][64 * RS];   // 64 rows (49 valid)
    __shared__ int pk[4][52];
    const int tid = threadIdx.x;
    const int w = tid >> 6, lane = tid & 63;
    const int b = blockIdx.y;
    const int bid  = blockIdx.x;                 // 0..783
    const int posb = (bid & 7) * 98 + (bid >> 3);   // XCD-contiguous spans
    const int pos0 = posb * 4;
    const int pos  = pos0 + w;
    const int y0 = pos / W_DIM, x0 = pos - y0 * W_DIM;
    const __fp16* __restrict__ base16 = xq + (size_t)b * HW_N * C_ALL;
    _Float16* tb = tbuf[w];
    // per-wave output staging aliases tbuf rows 49..63 (written only after
    // the wave's last read of rows <49; wave-private until __syncthreads)
    float* stage_w = (float*)(tb + 49 * RS);
    (void)cw2_b;   // cancels along the softmax axis

    const int quad = lane >> 4, l16 = lane & 15;

    // ---- hoisted: GEMM weight fragments + BN2 constants (phase-independent)
    g8 bf1[2], bf2[2];
    float iv2c[2], bt2c[2];
#pragma unroll
    for (int nt = 0; nt < 2; ++nt) {
        const float* wr1 = cw1 + (nt * 16 + l16) * C_R + quad * 8;
        bf1[nt] = pack8(*(const float4*)wr1, *(const float4*)(wr1 + 4));
        const float* wr2 = cw2 + (nt * 16 + l16) * C_R + quad * 8;
        bf2[nt] = pack8(*(const float4*)wr2, *(const float4*)(wr2 + 4));
        const int o = nt * 16 + l16;
        iv2c[nt] = bn2_g[o] * rsqrtf(bn2_v[o] + BN_EPS);
        bt2c[nt] = bn2_b[o] - bn2_m[o] * iv2c[nt];
    }

    // ---- phase 1: t[k][c] = relu(bn1(x1[c] - x2[pk(k)][c])) in f32, f16 pack
    // lane = r16*4 + c8: 8 channels per lane (16B loads), 16 rows per pass.
    {
        const int c8  = lane & 3;        // 8-ch block (ch = c8*8 .. +7)
        const int r16 = lane >> 2;       // row-in-pass 0..15
        const int cb  = c8 * 8;
        float niv[8], a1[8];             // niv = -iv; a1 = x1*iv + bt (f32)
        {
            float gg[8], bb_[8], mm[8], vv[8];
            *(float4*)(gg)      = *(const float4*)(bn1_g + cb);
            *(float4*)(gg + 4)  = *(const float4*)(bn1_g + cb + 4);
            *(float4*)(bb_)     = *(const float4*)(bn1_b + cb);
            *(float4*)(bb_ + 4) = *(const float4*)(bn1_b + cb + 4);
            *(float4*)(mm)      = *(const float4*)(bn1_m + cb);
            *(float4*)(mm + 4)  = *(const float4*)(bn1_m + cb + 4);
            *(float4*)(vv)      = *(const float4*)(bn1_v + cb);
            *(float4*)(vv + 4)  = *(const float4*)(bn1_v + cb + 4);
            const h8 x1v = *(const h8*)(base16 + (size_t)pos * C_ALL + cb);
#pragma unroll
            for (int j = 0; j < 8; ++j) {
                const float iv = gg[j] * rsqrtf(vv[j] + BN_EPS);
                const float bt = bb_[j] - mm[j] * iv;
                a1[j]  = fmaf((float)x1v[j], iv, bt);
                niv[j] = -iv;
            }
        }
        const h2 hz = {};

        auto bnrow = [&](int k) {
            const int dy = k / 7, dx = k - dy * 7;
            const int rp = refl(y0 + dy - 3) * W_DIM + refl(x0 + dx - 3);
            if (c8 == 0) pk[w][k] = rp;
            const h8 x2v = *(const h8*)(base16 + (size_t)rp * C_ALL + 32 + cb);
            float tv[8];
#pragma unroll
            for (int j = 0; j < 8; ++j)
                tv[j] = fmaf((float)x2v[j], niv[j], a1[j]);   // v_fma_mix
            h2 p0 = pkrtz(tv[0], tv[1]), p1 = pkrtz(tv[2], tv[3]);
            h2 p2 = pkrtz(tv[4], tv[5]), p3 = pkrtz(tv[6], tv[7]);
            p0 = __builtin_elementwise_max(p0, hz);
            p1 = __builtin_elementwise_max(p1, hz);
            p2 = __builtin_elementwise_max(p2, hz);
            p3 = __builtin_elementwise_max(p3, hz);
            u32x4 o;
            o[0] = __builtin_bit_cast(u32, p0);
            o[1] = __builtin_bit_cast(u32, p1);
            o[2] = __builtin_bit_cast(u32, p2);
            o[3] = __builtin_bit_cast(u32, p3);
            *(u32x4*)&tb[k * RS + cb] = o;          // 16B-aligned (80B rows)
        };
#pragma unroll
        for (int j = 0; j < 3; ++j) bnrow(j * 16 + r16);   // k = 0..47, no guard
        if (r16 == 0) bnrow(48);                           // tail row
    }
    wave_fence();

    // ---- early V-issue for phase 5: ALL rows. Addresses known now; loads
    // stay in flight across the lgkmcnt-only fences below and land under
    // GEMM1/BN2/GEMM2/softmax.
    const int hn5 = lane & 31;       // head == 8-ch block index
    const int hf5 = lane >> 5;       // 0: even k, 1: odd k
    const __fp16* vb5 = base16 + 64 + hn5 * 8;
    h8 pre[24];
#pragma unroll
    for (int i = 0; i < 24; ++i)
        pre[i] = *(const h8*)(vb5 + (size_t)pk[w][2 * i + hf5] * C_ALL);
    const h8 preT = *(const h8*)(vb5 + (size_t)pk[w][48] * C_ALL);  // k=48 (hf0 uses)

    f4 acc[4][2];

    // ---- phase 2 (GEMM1): Y1[k][o] = sum_c t[k][c] * cw1[o][c]
#pragma unroll
    for (int mt = 0; mt < 4; ++mt) {
        acc[mt][0] = (f4){0.f, 0.f, 0.f, 0.f};
        acc[mt][1] = (f4){0.f, 0.f, 0.f, 0.f};
        const g8 af = *(const g8*)((const __fp16*)tb + (mt * 16 + l16) * RS + quad * 8);
        acc[mt][0] = __builtin_amdgcn_mfma_f32_16x16x32_f16(af, bf1[0], acc[mt][0], 0, 0, 0);
        acc[mt][1] = __builtin_amdgcn_mfma_f32_16x16x32_f16(af, bf1[1], acc[mt][1], 0, 0, 0);
    }
    wave_fence();

    // ---- BN2 + ReLU on C-frags (col = output channel o), write y2[k][o]
#pragma unroll
    for (int nt = 0; nt < 2; ++nt) {
        const int o = nt * 16 + l16;
        const float iv = iv2c[nt], bt = bt2c[nt];
#pragma unroll
        for (int mt = 0; mt < 4; ++mt)
#pragma unroll
            for (int r = 0; r < 4; ++r) {
                const int row = mt * 16 + quad * 4 + r;
                tb[row * RS + o] = (_Float16)fmaxf(acc[mt][nt][r] * iv + bt, 0.f);
            }
    }
    wave_fence();

    // ---- phase 3 (GEMM2): logits[k][h] = sum_o y2[k][o] * cw2[h][o]
#pragma unroll
    for (int mt = 0; mt < 4; ++mt) {
        acc[mt][0] = (f4){0.f, 0.f, 0.f, 0.f};
        acc[mt][1] = (f4){0.f, 0.f, 0.f, 0.f};
        const g8 af = *(const g8*)((const __fp16*)tb + (mt * 16 + l16) * RS + quad * 8);
        acc[mt][0] = __builtin_amdgcn_mfma_f32_16x16x32_f16(af, bf2[0], acc[mt][0], 0, 0, 0);
        acc[mt][1] = __builtin_amdgcn_mfma_f32_16x16x32_f16(af, bf2[1], acc[mt][1], 0, 0, 0);
    }
    wave_fence();

    // ---- phase 4: softmax over k per head h = nt*16+l16; k = mt*16+quad*4+r
    // bias cancels along k; logits are O(1) for this problem -> no max-shift.
    // wgt writes limited to rows < 49 (stage alias lives in rows 49..63).
#pragma unroll
    for (int nt = 0; nt < 2; ++nt) {
        float s = 0.f;
#pragma unroll
        for (int mt = 0; mt < 4; ++mt)
#pragma unroll
            for (int r = 0; r < 4; ++r) {
                const int k = mt * 16 + quad * 4 + r;
                const float e = (k < K2D) ? __expf(acc[mt][nt][r]) : 0.f;
                acc[mt][nt][r] = e;
                s += e;
            }
        s += __shfl_xor(s, 16, 64);
        s += __shfl_xor(s, 32, 64);
        const float rs = 1.f / s;
        const int o = nt * 16 + l16;
#pragma unroll
        for (int mt = 0; mt < 4; ++mt)
#pragma unroll
            for (int r = 0; r < 4; ++r) {
                const int row = mt * 16 + quad * 4 + r;
                if (row < K2D)
                    tb[row * RS + o] = (_Float16)(acc[mt][nt][r] * rs);
            }
    }
    wave_fence();

    // ---- phase 5: out[c] = sum_k x3[pk[k]][c] * wgt[k][c>>3]
    // half-wave split: lanes 0..31 even k, 32..63 odd k; all V pre-loaded.
    {
        float a0 = 0.f, a1 = 0.f, a2 = 0.f, a3 = 0.f;
        float a4 = 0.f, a5 = 0.f, a6 = 0.f, a7 = 0.f;
#pragma unroll
        for (int i = 0; i < 24; ++i) {
            const int k = 2 * i + hf5;                     // <= 47, always valid
            const float wv = (float)tb[k * RS + hn5];
            const h8 v = pre[i];
            a0 = fmaf((float)v[0], wv, a0);
            a1 = fmaf((float)v[1], wv, a1);
            a2 = fmaf((float)v[2], wv, a2);
            a3 = fmaf((float)v[3], wv, a3);
            a4 = fmaf((float)v[4], wv, a4);
            a5 = fmaf((float)v[5], wv, a5);
            a6 = fmaf((float)v[6], wv, a6);
            a7 = fmaf((float)v[7], wv, a7);
        }
        if (hf5 == 0) {                                    // tail k = 48
            const float wv = (float)tb[48 * RS + hn5];
            const h8 v = preT;
            a0 = fmaf((float)v[0], wv, a0);
            a1 = fmaf((float)v[1], wv, a1);
            a2 = fmaf((float)v[2], wv, a2);
            a3 = fmaf((float)v[3], wv, a3);
            a4 = fmaf((float)v[4], wv, a4);
            a5 = fmaf((float)v[5], wv, a5);
            a6 = fmaf((float)v[6], wv, a6);
            a7 = fmaf((float)v[7], wv, a7);
        }
        a0 += __shfl_xor(a0, 32, 64);
        a1 += __shfl_xor(a1, 32, 64);
        a2 += __shfl_xor(a2, 32, 64);
        a3 += __shfl_xor(a3, 32, 64);
        a4 += __shfl_xor(a4, 32, 64);
        a5 += __shfl_xor(a5, 32, 64);
        a6 += __shfl_xor(a6, 32, 64);
        a7 += __shfl_xor(a7, 32, 64);
        if (hf5 == 0) {
            f4 o0 = {a0, a1, a2, a3};
            f4 o1 = {a4, a5, a6, a7};
            *(f4*)&stage_w[hn5 * 8]     = o0;
            *(f4*)&stage_w[hn5 * 8 + 4] = o1;
        }
    }
    __syncthreads();

    // ---- transpose through LDS: store out[b][c][pos0..pos0+3]
    {
        const int c = tid;
        const float* st0 = (const float*)(tbuf[0] + 49 * RS);
        const float* st1 = (const float*)(tbuf[1] + 49 * RS);
        const float* st2 = (const float*)(tbuf[2] + 49 * RS);
        const float* st3 = (const float*)(tbuf[3] + 49 * RS);
        float4 o;
        o.x = st0[c]; o.y = st1[c];
        o.z = st2[c]; o.w = st3[c];
        *(float4*)(out + ((size_t)b * C_OUT + c) * HW_N + pos0) = o;
    }
}

// ---------------------------------------------------------------------------
extern "C" void kernel_launch(void* const* d_in, const int* in_sizes, int n_in,
                              void* d_out, int out_size, void* d_ws, size_t ws_size,
                              hipStream_t stream)
{
    const float* x     = (const float*)d_in[0];
    const float* w1c   = (const float*)d_in[1];
    const float* b1c   = (const float*)d_in[2];
    const float* w2c   = (const float*)d_in[3];
    const float* b2c   = (const float*)d_in[4];
    const float* w3c   = (const float*)d_in[5];
    const float* b3c   = (const float*)d_in[6];
    const float* bn1_g = (const float*)d_in[7];
    const float* bn1_b = (const float*)d_in[8];
    const float* bn1_m = (const float*)d_in[9];
    const float* bn1_v = (const float*)d_in[10];
    const float* cw1   = (const float*)d_in[11];
    const float* bn2_g = (const float*)d_in[12];
    const float* bn2_b = (const float*)d_in[13];
    const float* bn2_m = (const float*)d_in[14];
    const float* bn2_v = (const float*)d_in[15];
    const float* cw2   = (const float*)d_in[16];
    const float* cw2_b = (const float*)d_in[17];

    __fp16* xall16 = (__fp16*)d_ws;                         // [4][3136][320] f16

    k_conv_mfma<<<dim3(98, 1, 4), 256, 0, stream>>>(x, w1c, w2c, w3c,
                                                    b1c, b2c, b3c, xall16);
    k_attn<<<dim3(784, 4, 1), 256, 0, stream>>>(xall16,
        bn1_g, bn1_b, bn1_m, bn1_v, cw1,
        bn2_g, bn2_b, bn2_m, bn2_v, cw2, cw2_b, (float*)d_out);
}

// Round 7
// 145.294 us; speedup vs baseline: 1.1589x; 1.1316x over previous
//
#include <hip/hip_runtime.h>
#include <math.h>

#define HW_N   3136
#define W_DIM  56
#define C_IN   256
#define C_R    32
#define C_OUT  256
#define C_ALL  320
#define K2D    49
#define RS     40        // attn t-row stride in halfs (80 B, 16B-aligned)
#define BN_EPS 1e-5f

typedef _Float16 h2 __attribute__((ext_vector_type(2)));
typedef _Float16 h4 __attribute__((ext_vector_type(4)));
typedef _Float16 h8 __attribute__((ext_vector_type(8)));
typedef __fp16  g2 __attribute__((ext_vector_type(2)));   // cvt_pkrtz return type
typedef __fp16  g4 __attribute__((ext_vector_type(4)));
typedef __fp16  g8 __attribute__((ext_vector_type(8)));
typedef float   f4 __attribute__((ext_vector_type(4)));
typedef unsigned int u32;
typedef unsigned int u32x4 __attribute__((ext_vector_type(4)));

__device__ __forceinline__ h2 pkrtz(float a, float b) {
    g2 r = __builtin_amdgcn_cvt_pkrtz(a, b);
    return __builtin_bit_cast(h2, r);
}

__device__ __forceinline__ g8 pack8(float4 a, float4 b) {
    g2 p0 = __builtin_amdgcn_cvt_pkrtz(a.x, a.y);
    g2 p1 = __builtin_amdgcn_cvt_pkrtz(a.z, a.w);
    g2 p2 = __builtin_amdgcn_cvt_pkrtz(b.x, b.y);
    g2 p3 = __builtin_amdgcn_cvt_pkrtz(b.z, b.w);
    g8 o;
    o[0] = p0[0]; o[1] = p0[1]; o[2] = p1[0]; o[3] = p1[1];
    o[4] = p2[0]; o[5] = p2[1]; o[6] = p3[0]; o[7] = p3[1];
    return o;
}

__device__ __forceinline__ int refl(int v) {
    v = (v < 0) ? -v : v;
    return (v > 55) ? (110 - v) : v;
}

// Wave-local "barrier": tbuf[w]/pk[w] are wave-private; DS pipe is in-order
// per wave, so we only need the compiler fence + lgkmcnt drain.
// NOTE: does NOT drain vmcnt -> prefetched global loads stay in flight.
__device__ __forceinline__ void wave_fence() {
    asm volatile("s_waitcnt lgkmcnt(0)" ::: "memory");
}

// ---------------------------------------------------------------------------
// Kernel 0: one-time weight conversion f32 -> f16, wall[co][ci], 160 KB.
// Removes 160 cvt_pkrtz + 40 float4-load pairs per lane per k_conv block
// (weights were being re-packed redundantly in all 392 blocks).
// ---------------------------------------------------------------------------
__global__ __launch_bounds__(256) void k_wconv(
    const float* __restrict__ w1c, const float* __restrict__ w2c,
    const float* __restrict__ w3c, __fp16* __restrict__ wall)
{
    const int co = blockIdx.x;           // 0..319
    const int ci = threadIdx.x;          // 0..255
    const float v = (co < 32) ? w1c[co * C_IN + ci]
                  : (co < 64) ? w2c[(co - 32) * C_IN + ci]
                              : w3c[(co - 64) * C_IN + ci];
    wall[co * C_IN + ci] = (__fp16)v;
}

// ---------------------------------------------------------------------------
// Kernel 1: fused transpose + MFMA conv1x1 -> xall16[b][pos][320] f16.
// 32-pos x 320-co tile per block, grid (98,1,4), 256 threads.
// ROUND-3 LESSON: 16-pos retile (784 blocks) regressed 17->43us.
// ROUND-5 LESSON: 512-thread 8-wave split regressed to ~37us. Do NOT re-tile.
// v7: weight loads now single g8 (16B) from pre-converted wall16 — halves
// weight issue count and removes all cvt from the hot loop; schedule intact.
// ---------------------------------------------------------------------------
__global__ __launch_bounds__(256) void k_conv_mfma(
    const float* __restrict__ x,
    const __fp16* __restrict__ wall,
    const float* __restrict__ b1c, const float* __restrict__ b2c,
    const float* __restrict__ b3c, __fp16* __restrict__ xall16)
{
    __shared__ __align__(16) _Float16 smem[32 * 328];   // staging 16KB / cs 21KB
    const int t = threadIdx.x, w = t >> 6, lane = t & 63;
    const int quad = lane >> 4, l16 = lane & 15;
    const int b = blockIdx.z, pos0 = blockIdx.x * 32;

    // ---- stage x[b][:][pos0..pos0+31] -> smem h8 slots [p][g], XOR-swizzled
    {
        const int p = t & 31;
        const int gb = t >> 5;               // 0..7
        const float* xp = x + (size_t)b * C_IN * HW_N + pos0 + p;
#pragma unroll
        for (int i = 0; i < 4; ++i) {
            const int g = i * 8 + gb;
            const int ci = g * 8;
            float v[8];
#pragma unroll
            for (int j = 0; j < 8; ++j) v[j] = xp[(size_t)(ci + j) * HW_N];
            g8 o;
#pragma unroll
            for (int jj = 0; jj < 4; ++jj) {
                const g2 pr = __builtin_amdgcn_cvt_pkrtz(v[2 * jj], v[2 * jj + 1]);
                o[2 * jj] = pr[0]; o[2 * jj + 1] = pr[1];
            }
            *(g8*)((__fp16*)smem + (size_t)(p * 32 + (g ^ (p & 7))) * 8) = o;
        }
    }
    __syncthreads();

    // weight rows (f16, pre-converted) + bias for this wave's 5 co-tiles
    const __fp16* wprow[5]; float bias[5];
#pragma unroll
    for (int nt = 0; nt < 5; ++nt) {
        const int co = w * 80 + nt * 16 + l16;
        wprow[nt] = wall + (size_t)co * C_IN;
        bias[nt] = (co < 32) ? b1c[co] : (co < 64) ? b2c[co - 32] : b3c[co - 64];
    }

    f4 acc[2][5];
#pragma unroll
    for (int mt = 0; mt < 2; ++mt)
#pragma unroll
        for (int nt = 0; nt < 5; ++nt) acc[mt][nt] = (f4){0.f, 0.f, 0.f, 0.f};

    const int xo = l16 & 7;
#pragma unroll
    for (int ks = 0; ks < 8; ++ks) {
        g8 bf[5];
#pragma unroll
        for (int nt = 0; nt < 5; ++nt)
            bf[nt] = *(const g8*)(wprow[nt] + ks * 32 + quad * 8);
#pragma unroll
        for (int mt = 0; mt < 2; ++mt) {
            const int row = mt * 16 + l16;
            const g8 af = *(const g8*)((const __fp16*)smem
                          + (size_t)(row * 32 + ((ks * 4 + quad) ^ xo)) * 8);
#pragma unroll
            for (int nt = 0; nt < 5; ++nt)
                acc[mt][nt] = __builtin_amdgcn_mfma_f32_16x16x32_f16(af, bf[nt], acc[mt][nt], 0, 0, 0);
        }
    }
    __syncthreads();   // all A-frag reads done before smem is reused

    // ---- epilogue: C-frags -> smem f16 [32][328], then coalesced h8 stores
#pragma unroll
    for (int mt = 0; mt < 2; ++mt)
#pragma unroll
        for (int nt = 0; nt < 5; ++nt) {
            const int co = w * 80 + nt * 16 + l16;
#pragma unroll
            for (int r = 0; r < 4; ++r) {
                const int row = mt * 16 + quad * 4 + r;
                smem[row * 328 + co] = (_Float16)(acc[mt][nt][r] + bias[nt]);
            }
        }
    __syncthreads();
#pragma unroll
    for (int i = 0; i < 5; ++i) {
        const int idx = i * 256 + t;        // 0..1279 = 32 rows x 40 h8
        const int row = idx / 40, c8 = idx - row * 40;
        const g8 v = *(const g8*)((const __fp16*)smem + row * 328 + c8 * 8);
        *(g8*)(xall16 + ((size_t)b * HW_N + pos0 + row) * C_ALL + c8 * 8) = v;
    }
}

// ---------------------------------------------------------------------------
// Kernel 2: fused attention + output transpose. One wave per pixel,
// 4 waves/block; single block barrier at the very end for the transpose.
// v4 EXACT (measured 42.1us). ROUND-6 LESSON: pre[24] prefetch spills
// (VGPR cap ~100, occ 19%, 64us) — 12-deep is the proven depth. Unchanged.
// ---------------------------------------------------------------------------
__global__ __launch_bounds__(256) void k_attn(
    const __fp16* __restrict__ xq,
    const float* __restrict__ bn1_g, const float* __restrict__ bn1_b,
    const float* __restrict__ bn1_m, const float* __restrict__ bn1_v,
    const float* __restrict__ cw1,
    const float* __restrict__ bn2_g, const float* __restrict__ bn2_b,
    const float* __restrict__ bn2_m, const float* __restrict__ bn2_v,
    const float* __restrict__ cw2, const float* __restrict__ cw2_b,
    float* __restrict__ out)
{
    __shared__ __align__(16) _Float16 tbuf[4][64 * RS];   // 64 rows (49 valid)
    __shared__ int pk[4][52];
    const int tid = threadIdx.x;
    const int w = tid >> 6, lane = tid & 63;
    const int b = blockIdx.y;
    const int bid  = blockIdx.x;                 // 0..783
    const int posb = (bid & 7) * 98 + (bid >> 3);   // XCD-contiguous spans
    const int pos0 = posb * 4;
    const int pos  = pos0 + w;
    const int y0 = pos / W_DIM, x0 = pos - y0 * W_DIM;
    const __fp16* __restrict__ base16 = xq + (size_t)b * HW_N * C_ALL;
    _Float16* tb = tbuf[w];
    // per-wave output staging aliases tbuf rows 49..63 (written only after
    // the wave's last read of rows <49; wave-private until __syncthreads)
    float* stage_w = (float*)(tb + 49 * RS);
    (void)cw2_b;   // cancels along the softmax axis

    const int quad = lane >> 4, l16 = lane & 15;

    // ---- hoisted: GEMM weight fragments + BN2 constants (phase-independent)
    g8 bf1[2], bf2[2];
    float iv2c[2], bt2c[2];
#pragma unroll
    for (int nt = 0; nt < 2; ++nt) {
        const float* wr1 = cw1 + (nt * 16 + l16) * C_R + quad * 8;
        bf1[nt] = pack8(*(const float4*)wr1, *(const float4*)(wr1 + 4));
        const float* wr2 = cw2 + (nt * 16 + l16) * C_R + quad * 8;
        bf2[nt] = pack8(*(const float4*)wr2, *(const float4*)(wr2 + 4));
        const int o = nt * 16 + l16;
        iv2c[nt] = bn2_g[o] * rsqrtf(bn2_v[o] + BN_EPS);
        bt2c[nt] = bn2_b[o] - bn2_m[o] * iv2c[nt];
    }

    // ---- phase 1: t[k][c] = relu(bn1(x1[c] - x2[pk(k)][c])) in f32, f16 pack
    // lane = r16*4 + c8: 8 channels per lane (16B loads), 16 rows per pass.
    {
        const int c8  = lane & 3;        // 8-ch block (ch = c8*8 .. +7)
        const int r16 = lane >> 2;       // row-in-pass 0..15
        const int cb  = c8 * 8;
        float niv[8], a1[8];             // niv = -iv; a1 = x1*iv + bt (f32)
        {
            float gg[8], bb_[8], mm[8], vv[8];
            *(float4*)(gg)      = *(const float4*)(bn1_g + cb);
            *(float4*)(gg + 4)  = *(const float4*)(bn1_g + cb + 4);
            *(float4*)(bb_)     = *(const float4*)(bn1_b + cb);
            *(float4*)(bb_ + 4) = *(const float4*)(bn1_b + cb + 4);
            *(float4*)(mm)      = *(const float4*)(bn1_m + cb);
            *(float4*)(mm + 4)  = *(const float4*)(bn1_m + cb + 4);
            *(float4*)(vv)      = *(const float4*)(bn1_v + cb);
            *(float4*)(vv + 4)  = *(const float4*)(bn1_v + cb + 4);
            const h8 x1v = *(const h8*)(base16 + (size_t)pos * C_ALL + cb);
#pragma unroll
            for (int j = 0; j < 8; ++j) {
                const float iv = gg[j] * rsqrtf(vv[j] + BN_EPS);
                const float bt = bb_[j] - mm[j] * iv;
                a1[j]  = fmaf((float)x1v[j], iv, bt);
                niv[j] = -iv;
            }
        }
        const h2 hz = {};

        auto bnrow = [&](int k) {
            const int dy = k / 7, dx = k - dy * 7;
            const int rp = refl(y0 + dy - 3) * W_DIM + refl(x0 + dx - 3);
            if (c8 == 0) pk[w][k] = rp;
            const h8 x2v = *(const h8*)(base16 + (size_t)rp * C_ALL + 32 + cb);
            float tv[8];
#pragma unroll
            for (int j = 0; j < 8; ++j)
                tv[j] = fmaf((float)x2v[j], niv[j], a1[j]);   // v_fma_mix
            h2 p0 = pkrtz(tv[0], tv[1]), p1 = pkrtz(tv[2], tv[3]);
            h2 p2 = pkrtz(tv[4], tv[5]), p3 = pkrtz(tv[6], tv[7]);
            p0 = __builtin_elementwise_max(p0, hz);
            p1 = __builtin_elementwise_max(p1, hz);
            p2 = __builtin_elementwise_max(p2, hz);
            p3 = __builtin_elementwise_max(p3, hz);
            u32x4 o;
            o[0] = __builtin_bit_cast(u32, p0);
            o[1] = __builtin_bit_cast(u32, p1);
            o[2] = __builtin_bit_cast(u32, p2);
            o[3] = __builtin_bit_cast(u32, p3);
            *(u32x4*)&tb[k * RS + cb] = o;          // 16B-aligned (80B rows)
        };
#pragma unroll
        for (int j = 0; j < 3; ++j) bnrow(j * 16 + r16);   // k = 0..47, no guard
        if (r16 == 0) bnrow(48);                           // tail row
    }
    wave_fence();

    // ---- early V-issue for phase 5 (addresses known now; loads stay in
    // flight across the lgkmcnt-only fences below). Depth 12 PROVEN; 24 spills.
    const int hn5 = lane & 31;       // head == 8-ch block index
    const int hf5 = lane >> 5;       // 0: even k, 1: odd k
    const __fp16* vb5 = base16 + 64 + hn5 * 8;
    h8 pre[12];
#pragma unroll
    for (int i = 0; i < 12; ++i)
        pre[i] = *(const h8*)(vb5 + (size_t)pk[w][2 * i + hf5] * C_ALL);

    f4 acc[4][2];

    // ---- phase 2 (GEMM1): Y1[k][o] = sum_c t[k][c] * cw1[o][c]
#pragma unroll
    for (int mt = 0; mt < 4; ++mt) {
        acc[mt][0] = (f4){0.f, 0.f, 0.f, 0.f};
        acc[mt][1] = (f4){0.f, 0.f, 0.f, 0.f};
        const g8 af = *(const g8*)((const __fp16*)tb + (mt * 16 + l16) * RS + quad * 8);
        acc[mt][0] = __builtin_amdgcn_mfma_f32_16x16x32_f16(af, bf1[0], acc[mt][0], 0, 0, 0);
        acc[mt][1] = __builtin_amdgcn_mfma_f32_16x16x32_f16(af, bf1[1], acc[mt][1], 0, 0, 0);
    }
    wave_fence();

    // ---- BN2 + ReLU on C-frags (col = output channel o), write y2[k][o]
#pragma unroll
    for (int nt = 0; nt < 2; ++nt) {
        const int o = nt * 16 + l16;
        const float iv = iv2c[nt], bt = bt2c[nt];
#pragma unroll
        for (int mt = 0; mt < 4; ++mt)
#pragma unroll
            for (int r = 0; r < 4; ++r) {
                const int row = mt * 16 + quad * 4 + r;
                tb[row * RS + o] = (_Float16)fmaxf(acc[mt][nt][r] * iv + bt, 0.f);
            }
    }
    wave_fence();

    // ---- phase 3 (GEMM2): logits[k][h] = sum_o y2[k][o] * cw2[h][o]
#pragma unroll
    for (int mt = 0; mt < 4; ++mt) {
        acc[mt][0] = (f4){0.f, 0.f, 0.f, 0.f};
        acc[mt][1] = (f4){0.f, 0.f, 0.f, 0.f};
        const g8 af = *(const g8*)((const __fp16*)tb + (mt * 16 + l16) * RS + quad * 8);
        acc[mt][0] = __builtin_amdgcn_mfma_f32_16x16x32_f16(af, bf2[0], acc[mt][0], 0, 0, 0);
        acc[mt][1] = __builtin_amdgcn_mfma_f32_16x16x32_f16(af, bf2[1], acc[mt][1], 0, 0, 0);
    }
    wave_fence();

    // ---- phase 4: softmax over k per head h = nt*16+l16; k = mt*16+quad*4+r
    // bias cancels along k; logits are O(1) for this problem -> no max-shift.
    // wgt writes limited to rows < 49 (stage alias lives in rows 49..63).
#pragma unroll
    for (int nt = 0; nt < 2; ++nt) {
        float s = 0.f;
#pragma unroll
        for (int mt = 0; mt < 4; ++mt)
#pragma unroll
            for (int r = 0; r < 4; ++r) {
                const int k = mt * 16 + quad * 4 + r;
                const float e = (k < K2D) ? __expf(acc[mt][nt][r]) : 0.f;
                acc[mt][nt][r] = e;
                s += e;
            }
        s += __shfl_xor(s, 16, 64);
        s += __shfl_xor(s, 32, 64);
        const float rs = 1.f / s;
        const int o = nt * 16 + l16;
#pragma unroll
        for (int mt = 0; mt < 4; ++mt)
#pragma unroll
            for (int r = 0; r < 4; ++r) {
                const int row = mt * 16 + quad * 4 + r;
                if (row < K2D)
                    tb[row * RS + o] = (_Float16)(acc[mt][nt][r] * rs);
            }
    }
    wave_fence();

    // ---- phase 5: out[c] = sum_k x3[pk[k]][c] * wgt[k][c>>3]
    // half-wave split: lanes 0..31 even k, 32..63 odd k; 8 ch/lane (16B loads)
    {
        float a0 = 0.f, a1 = 0.f, a2 = 0.f, a3 = 0.f;
        float a4 = 0.f, a5 = 0.f, a6 = 0.f, a7 = 0.f;
#pragma unroll
        for (int i = 0; i < 12; ++i) {                     // prefetched rows
            const int k = 2 * i + hf5;
            const float wv = (float)tb[k * RS + hn5];
            const h8 v = pre[i];
            a0 = fmaf((float)v[0], wv, a0);
            a1 = fmaf((float)v[1], wv, a1);
            a2 = fmaf((float)v[2], wv, a2);
            a3 = fmaf((float)v[3], wv, a3);
            a4 = fmaf((float)v[4], wv, a4);
            a5 = fmaf((float)v[5], wv, a5);
            a6 = fmaf((float)v[6], wv, a6);
            a7 = fmaf((float)v[7], wv, a7);
        }
#pragma unroll 6
        for (int i = 12; i < 24; ++i) {
            const int k = 2 * i + hf5;                     // <= 47, always valid
            const int rp = pk[w][k];
            const float wv = (float)tb[k * RS + hn5];
            const h8 v = *(const h8*)(vb5 + (size_t)rp * C_ALL);
            a0 = fmaf((float)v[0], wv, a0);
            a1 = fmaf((float)v[1], wv, a1);
            a2 = fmaf((float)v[2], wv, a2);
            a3 = fmaf((float)v[3], wv, a3);
            a4 = fmaf((float)v[4], wv, a4);
            a5 = fmaf((float)v[5], wv, a5);
            a6 = fmaf((float)v[6], wv, a6);
            a7 = fmaf((float)v[7], wv, a7);
        }
        if (hf5 == 0) {                                    // tail k = 48
            const int rp = pk[w][48];
            const float wv = (float)tb[48 * RS + hn5];
            const h8 v = *(const h8*)(vb5 + (size_t)rp * C_ALL);
            a0 = fmaf((float)v[0], wv, a0);
            a1 = fmaf((float)v[1], wv, a1);
            a2 = fmaf((float)v[2], wv, a2);
            a3 = fmaf((float)v[3], wv, a3);
            a4 = fmaf((float)v[4], wv, a4);
            a5 = fmaf((float)v[5], wv, a5);
            a6 = fmaf((float)v[6], wv, a6);
            a7 = fmaf((float)v[7], wv, a7);
        }
        a0 += __shfl_xor(a0, 32, 64);
        a1 += __shfl_xor(a1, 32, 64);
        a2 += __shfl_xor(a2, 32, 64);
        a3 += __shfl_xor(a3, 32, 64);
        a4 += __shfl_xor(a4, 32, 64);
        a5 += __shfl_xor(a5, 32, 64);
        a6 += __shfl_xor(a6, 32, 64);
        a7 += __shfl_xor(a7, 32, 64);
        if (hf5 == 0) {
            f4 o0 = {a0, a1, a2, a3};
            f4 o1 = {a4, a5, a6, a7};
            *(f4*)&stage_w[hn5 * 8]     = o0;
            *(f4*)&stage_w[hn5 * 8 + 4] = o1;
        }
    }
    __syncthreads();

    // ---- transpose through LDS: store out[b][c][pos0..pos0+3]
    {
        const int c = tid;
        const float* st0 = (const float*)(tbuf[0] + 49 * RS);
        const float* st1 = (const float*)(tbuf[1] + 49 * RS);
        const float* st2 = (const float*)(tbuf[2] + 49 * RS);
        const float* st3 = (const float*)(tbuf[3] + 49 * RS);
        float4 o;
        o.x = st0[c]; o.y = st1[c];
        o.z = st2[c]; o.w = st3[c];
        *(float4*)(out + ((size_t)b * C_OUT + c) * HW_N + pos0) = o;
    }
}

// ---------------------------------------------------------------------------
extern "C" void kernel_launch(void* const* d_in, const int* in_sizes, int n_in,
                              void* d_out, int out_size, void* d_ws, size_t ws_size,
                              hipStream_t stream)
{
    const float* x     = (const float*)d_in[0];
    const float* w1c   = (const float*)d_in[1];
    const float* b1c   = (const float*)d_in[2];
    const float* w2c   = (const float*)d_in[3];
    const float* b2c   = (const float*)d_in[4];
    const float* w3c   = (const float*)d_in[5];
    const float* b3c   = (const float*)d_in[6];
    const float* bn1_g = (const float*)d_in[7];
    const float* bn1_b = (const float*)d_in[8];
    const float* bn1_m = (const float*)d_in[9];
    const float* bn1_v = (const float*)d_in[10];
    const float* cw1   = (const float*)d_in[11];
    const float* bn2_g = (const float*)d_in[12];
    const float* bn2_b = (const float*)d_in[13];
    const float* bn2_m = (const float*)d_in[14];
    const float* bn2_v = (const float*)d_in[15];
    const float* cw2   = (const float*)d_in[16];
    const float* cw2_b = (const float*)d_in[17];

    __fp16* xall16 = (__fp16*)d_ws;                         // [4][3136][320] f16
    __fp16* wall16 = xall16 + (size_t)4 * HW_N * C_ALL;     // [320][256] f16

    k_wconv<<<dim3(320, 1, 1), 256, 0, stream>>>(w1c, w2c, w3c, wall16);
    k_conv_mfma<<<dim3(98, 1, 4), 256, 0, stream>>>(x, wall16,
                                                    b1c, b2c, b3c, xall16);
    k_attn<<<dim3(784, 4, 1), 256, 0, stream>>>(xall16,
        bn1_g, bn1_b, bn1_m, bn1_v, cw1,
        bn2_g, bn2_b, bn2_m, bn2_v, cw2, cw2_b, (float*)d_out);
}